// Round 12
// baseline (48343.845 us; speedup 1.0000x reference)
//
#include <hip/hip_runtime.h>
#include <math.h>

#define T_STEPS 2048
#define B_SZ 32
#define F_SZ 512
#define H_SZ 512
#define H4_SZ 2048
#define NC_SZ 64
#define NBLK 64
#define NGRID 256            // 64 workers + 192 memory-streaming heater blocks
#define RINGE 16384          // fp16 elems per ring slot (32 KB), fragment-ordered
#define FLAG_STRIDE 32       // u32s -> 128 B: one LLC line per block's flag
#define HEAT_CAP 8192        // heater outer bound (~0.3 s worst case) — can't hang
#define TOTAL4 ((B_SZ * T_STEPS * F_SZ) / 4)   // feats in float4 units, 2^23

typedef _Float16 f16x8 __attribute__((ext_vector_type(8)));
typedef float f32x4 __attribute__((ext_vector_type(4)));

#define TIDX(l, w, rt, ct) (((((l)*4 + (w))*2 + (rt))*2 + (ct)))

// Batched LLC-coherent h-load (r8, best-known): fragment-ordered ring ->
// wave's 64 lanes load CONTIGUOUS 1KB per dwordx4; one vmcnt(0) for all 16.
// Ring slot layout: [kql(2)][ks(8)][rt(2)][lane(64)][i(8)] fp16.
#define LDFRAG16(d, a0, a1, a2, a3)                                             \
  asm volatile(                                                                 \
    "global_load_dwordx4 %0, %16, off sc0 sc1\n\t"                              \
    "global_load_dwordx4 %1, %16, off offset:1024 sc0 sc1\n\t"                  \
    "global_load_dwordx4 %2, %16, off offset:2048 sc0 sc1\n\t"                  \
    "global_load_dwordx4 %3, %16, off offset:3072 sc0 sc1\n\t"                  \
    "global_load_dwordx4 %4, %17, off sc0 sc1\n\t"                              \
    "global_load_dwordx4 %5, %17, off offset:1024 sc0 sc1\n\t"                  \
    "global_load_dwordx4 %6, %17, off offset:2048 sc0 sc1\n\t"                  \
    "global_load_dwordx4 %7, %17, off offset:3072 sc0 sc1\n\t"                  \
    "global_load_dwordx4 %8, %18, off sc0 sc1\n\t"                              \
    "global_load_dwordx4 %9, %18, off offset:1024 sc0 sc1\n\t"                  \
    "global_load_dwordx4 %10, %18, off offset:2048 sc0 sc1\n\t"                 \
    "global_load_dwordx4 %11, %18, off offset:3072 sc0 sc1\n\t"                 \
    "global_load_dwordx4 %12, %19, off sc0 sc1\n\t"                             \
    "global_load_dwordx4 %13, %19, off offset:1024 sc0 sc1\n\t"                 \
    "global_load_dwordx4 %14, %19, off offset:2048 sc0 sc1\n\t"                 \
    "global_load_dwordx4 %15, %19, off offset:3072 sc0 sc1\n\t"                 \
    "s_waitcnt vmcnt(0)"                                                        \
    : "=&v"(d[0][0]), "=&v"(d[1][0]), "=&v"(d[0][1]), "=&v"(d[1][1]),           \
      "=&v"(d[0][2]), "=&v"(d[1][2]), "=&v"(d[0][3]), "=&v"(d[1][3]),           \
      "=&v"(d[0][4]), "=&v"(d[1][4]), "=&v"(d[0][5]), "=&v"(d[1][5]),           \
      "=&v"(d[0][6]), "=&v"(d[1][6]), "=&v"(d[0][7]), "=&v"(d[1][7])            \
    : "v"(a0), "v"(a1), "v"(a2), "v"(a3)                                        \
    : "memory")

// Persistent 2-layer LSTM. Workers (jb<64): r8 structure byte-identical
// (best known, 32.1ms steady). Heaters (jb>=64): STREAM MEMORY, not VALU —
// r7's VALU heaters raised shader-domain activity and changed NOTHING; the
// h-exchange is fabric/LLC-latency-bound, and the fabric/memory clocks
// (fclk/uclk) are governed by MEMORY traffic. Workers' steady 40 GB/s (0.5%)
// parks fclk at floor -> every fabric traversal is ~4-8x spec latency ->
// the protocol-invariant ~14us/iter floor. Heaters stream feats (134MB:
// bigger than aggregate L2, LLC-resident after first pass) to pin the
// memory domain at full clock on exactly the path the h-exchange uses.
__global__ __launch_bounds__(256, 1) void lstm_persistent(
    const float* __restrict__ feats,
    const float* __restrict__ Wi0, const float* __restrict__ Wh0,
    const float* __restrict__ bh0,
    const float* __restrict__ Wi1, const float* __restrict__ Wh1,
    const float* __restrict__ bh1,
    const float* __restrict__ Wout, const float* __restrict__ bout,
    float* __restrict__ out,
    _Float16* __restrict__ h0ring,  // [2][RINGE] fp16, fragment-ordered
    _Float16* __restrict__ h1ring,  // [2][RINGE] fp16, fragment-ordered
    float* __restrict__ h1fin,      // [32][512] f32 final h1
    unsigned* __restrict__ flags,   // [64 * FLAG_STRIDE] per-block flags, padded
    unsigned* __restrict__ done)    // heater shutdown flag
{
    const int tid = threadIdx.x;
    const int jb  = blockIdx.x;

    // ---- heater path: stream feats through LLC/fabric until workers finish ----
    if (jb >= NBLK) {
        const int h = jb - NBLK;                    // 0..191
        const float4* src = (const float4*)feats;
        float acc = 0.f;
        for (int outer = 0; outer < HEAT_CAP; ++outer) {
            const unsigned base = (unsigned)h * 43691u + (unsigned)outer * 524309u;
            float s = 0.f;
            #pragma unroll 8
            for (int c = 0; c < 256; ++c) {
                const unsigned idx = (base + (unsigned)c * 1024u + (unsigned)tid)
                                     & (TOTAL4 - 1);
                const float4 v = src[idx];
                s += v.x + v.y + v.z + v.w;
            }
            acc += s;
            asm volatile("" :: "v"(acc));           // keep the stream live
            unsigned f;
            asm volatile("global_load_dword %0, %1, off sc0 sc1\n\t"
                         "s_waitcnt vmcnt(0)"
                         : "=&v"(f) : "v"(done) : "memory");
            if (f) break;
        }
        return;
    }

    const int lane  = tid & 63;
    const int wv    = tid >> 6;          // wave 0..3 = K-quarter of stacked K=1024
    const int hbase = jb * 8;
    const int rlane = lane & 15;
    const int klo   = (lane >> 4) * 8;

    __shared__ float zs[32 * 272];       // 32 tiles of 16x17 f32 partials
    __shared__ float ps[256];

    // ---- one-time: weight fragments (fp16) ----
    // layer0 stacked K: [Wi0(512); Wh0(512)], A0 = [x | h0]
    // layer1 stacked K: [Wh1(512); Wi1(512)], A1 = [h1 | h0]
    // B frag 16x16x32: lane holds col=lane&15, k=(lane>>4)*8+i  (verified r1)
    f16x8 wf0[2][8], wf1[2][8];
    #pragma unroll
    for (int ct = 0; ct < 2; ++ct) {
        const int cc   = ct * 16 + rlane;
        const int jcol = (cc >> 3) * H_SZ + hbase + (cc & 7);
        #pragma unroll
        for (int ks = 0; ks < 8; ++ks) {
            const int k0 = 256 * wv + 32 * ks + klo;
            f16x8 f0, f1;
            #pragma unroll
            for (int i = 0; i < 8; ++i) {
                const int k = k0 + i;
                const float v0 = (k < H_SZ) ? Wi0[(size_t)k * H4_SZ + jcol]
                                            : Wh0[(size_t)(k - H_SZ) * H4_SZ + jcol];
                const float v1 = (k < H_SZ) ? Wh1[(size_t)k * H4_SZ + jcol]
                                            : Wi1[(size_t)(k - H_SZ) * H4_SZ + jcol];
                f0[i] = (_Float16)v0;
                f1[i] = (_Float16)v1;
            }
            wf0[ct][ks] = f0;
            wf1[ct][ks] = f1;
        }
    }

    // gate-thread mapping: all 256 threads, one (batch,unit) each
    const int gb = tid >> 3, gu = tid & 7;
    const int grow = gb & 15, grt = gb >> 4;
    float c0 = 0.f, c1 = 0.f;
    float bias0[4], bias1[4];
    #pragma unroll
    for (int g = 0; g < 4; ++g) {
        bias0[g] = bh0[g * H_SZ + hbase + gu];
        bias1[g] = bh1[g * H_SZ + hbase + gu];
    }
    // producer scatter index into fragment-ordered ring for value (b=gb,
    // u=hbase+gu): kql=jb>>5, ks=(jb>>2)&7, lane=(jb&3)*16+(gb&15), rt=gb>>4
    const int eidx = (jb >> 5) * 8192
                   + ((((jb >> 2) & 7) * 2) + (gb >> 4)) * 512
                   + ((jb & 3) * 16 + (gb & 15)) * 8 + gu;

    f16x8 xf[2][8];   // prefetched+converted x fragments (waves 0,1)

#define PREFETCH_X(tt_) do {                                                         \
    if (wv < 2 && (tt_) < T_STEPS) {                                                 \
        _Pragma("unroll")                                                            \
        for (int rt = 0; rt < 2; ++rt) {                                             \
            const float* xr = feats                                                  \
                + ((size_t)(rt * 16 + rlane) * T_STEPS + (size_t)(tt_)) * F_SZ       \
                + 256 * wv + klo;                                                    \
            _Pragma("unroll")                                                        \
            for (int ks = 0; ks < 8; ++ks) {                                         \
                const float4 p0 = *(const float4*)(xr + 32 * ks);                    \
                const float4 p1 = *(const float4*)(xr + 32 * ks + 4);                \
                f16x8 t;                                                             \
                t[0] = (_Float16)p0.x; t[1] = (_Float16)p0.y;                        \
                t[2] = (_Float16)p0.z; t[3] = (_Float16)p0.w;                        \
                t[4] = (_Float16)p1.x; t[5] = (_Float16)p1.y;                        \
                t[6] = (_Float16)p1.z; t[7] = (_Float16)p1.w;                        \
                xf[rt][ks] = t;                                                      \
            }                                                                        \
        }                                                                            \
    }                                                                                \
} while (0)

    PREFETCH_X(0);

    for (int it = 0; it <= T_STEPS; ++it) {
        // ---- distributed barrier: each poll lane owns one padded flag line ----
        if (tid < 64) {
            while (__hip_atomic_load(&flags[(size_t)lane * FLAG_STRIDE],
                                     __ATOMIC_RELAXED, __HIP_MEMORY_SCOPE_AGENT)
                   < (unsigned)it) { }
        }
        __syncthreads();

        // ---- h fragments: fully-coalesced fragment-ordered loads ----
        // wv>=2: h0[it-1] slot (it+1)&1, kql=wv-2 (shared by layer0 & layer1)
        // wv<2 : h1[it-2] slot it&1,     kql=wv
        f16x8 hA[2][8];
        if (wv >= 2) {
            const _Float16* b = h0ring + (size_t)((it + 1) & 1) * RINGE
                                + (wv - 2) * 8192 + lane * 8;
            LDFRAG16(hA, b, b + 2048, b + 4096, b + 6144);
        } else if (it > 0) {
            const _Float16* b = h1ring + (size_t)(it & 1) * RINGE
                                + wv * 8192 + lane * 8;
            LDFRAG16(hA, b, b + 2048, b + 4096, b + 6144);
        }

        const int r0 = (lane >> 4) * 4, ccl = lane & 15;

        // ---- layer0 MFMA (t=it): A = x (wv<2, in regs) or h0 (wv>=2) ----
        if (it < T_STEPS) {
            f32x4 a00 = {0,0,0,0}, a01 = {0,0,0,0}, a10 = {0,0,0,0}, a11 = {0,0,0,0};
            #pragma unroll
            for (int ks = 0; ks < 8; ++ks) {
                const f16x8 ar0 = (wv < 2) ? xf[0][ks] : hA[0][ks];
                const f16x8 ar1 = (wv < 2) ? xf[1][ks] : hA[1][ks];
                a00 = __builtin_amdgcn_mfma_f32_16x16x32_f16(ar0, wf0[0][ks], a00, 0, 0, 0);
                a01 = __builtin_amdgcn_mfma_f32_16x16x32_f16(ar0, wf0[1][ks], a01, 0, 0, 0);
                a10 = __builtin_amdgcn_mfma_f32_16x16x32_f16(ar1, wf0[0][ks], a10, 0, 0, 0);
                a11 = __builtin_amdgcn_mfma_f32_16x16x32_f16(ar1, wf0[1][ks], a11, 0, 0, 0);
            }
            #pragma unroll
            for (int q = 0; q < 4; ++q) {
                zs[TIDX(0, wv, 0, 0) * 272 + (r0 + q) * 17 + ccl] = a00[q];
                zs[TIDX(0, wv, 0, 1) * 272 + (r0 + q) * 17 + ccl] = a01[q];
                zs[TIDX(0, wv, 1, 0) * 272 + (r0 + q) * 17 + ccl] = a10[q];
                zs[TIDX(0, wv, 1, 1) * 272 + (r0 + q) * 17 + ccl] = a11[q];
            }
        }
        // ---- layer1 MFMA (t=it-1): A = h1 (wv<2) or h0 (wv>=2) = hA ----
        if (it > 0) {
            f32x4 a00 = {0,0,0,0}, a01 = {0,0,0,0}, a10 = {0,0,0,0}, a11 = {0,0,0,0};
            #pragma unroll
            for (int ks = 0; ks < 8; ++ks) {
                a00 = __builtin_amdgcn_mfma_f32_16x16x32_f16(hA[0][ks], wf1[0][ks], a00, 0, 0, 0);
                a01 = __builtin_amdgcn_mfma_f32_16x16x32_f16(hA[0][ks], wf1[1][ks], a01, 0, 0, 0);
                a10 = __builtin_amdgcn_mfma_f32_16x16x32_f16(hA[1][ks], wf1[0][ks], a10, 0, 0, 0);
                a11 = __builtin_amdgcn_mfma_f32_16x16x32_f16(hA[1][ks], wf1[1][ks], a11, 0, 0, 0);
            }
            #pragma unroll
            for (int q = 0; q < 4; ++q) {
                zs[TIDX(1, wv, 0, 0) * 272 + (r0 + q) * 17 + ccl] = a00[q];
                zs[TIDX(1, wv, 0, 1) * 272 + (r0 + q) * 17 + ccl] = a01[q];
                zs[TIDX(1, wv, 1, 0) * 272 + (r0 + q) * 17 + ccl] = a10[q];
                zs[TIDX(1, wv, 1, 1) * 272 + (r0 + q) * 17 + ccl] = a11[q];
            }
        }
        __syncthreads();

        // ---- gates: reduce 4 K-partials, update c, scatter h into frag ring ----
        if (it < T_STEPS) {
            float z[4];
            #pragma unroll
            for (int g = 0; g < 4; ++g) {
                const int cc = g * 8 + gu, ct = cc >> 4, col = cc & 15;
                float v = bias0[g];
                #pragma unroll
                for (int w = 0; w < 4; ++w)
                    v += zs[TIDX(0, w, grt, ct) * 272 + grow * 17 + col];
                z[g] = v;
            }
            const float ig = 1.f / (1.f + expf(-z[0]));
            const float fg = 1.f / (1.f + expf(-z[1]));
            const float gg = tanhf(z[2]);
            const float og = 1.f / (1.f + expf(-z[3]));
            c0 = fg * c0 + ig * gg;
            const float hv = og * tanhf(c0);
            union { _Float16 h; unsigned short s; } cv; cv.h = (_Float16)hv;
            __hip_atomic_store(
                (unsigned short*)(h0ring + (size_t)(it & 1) * RINGE + eidx),
                cv.s, __ATOMIC_RELAXED, __HIP_MEMORY_SCOPE_AGENT);
        }
        if (it > 0) {
            float z[4];
            #pragma unroll
            for (int g = 0; g < 4; ++g) {
                const int cc = g * 8 + gu, ct = cc >> 4, col = cc & 15;
                float v = bias1[g];
                #pragma unroll
                for (int w = 0; w < 4; ++w)
                    v += zs[TIDX(1, w, grt, ct) * 272 + grow * 17 + col];
                z[g] = v;
            }
            const float ig = 1.f / (1.f + expf(-z[0]));
            const float fg = 1.f / (1.f + expf(-z[1]));
            const float gg = tanhf(z[2]);
            const float og = 1.f / (1.f + expf(-z[3]));
            c1 = fg * c1 + ig * gg;
            const float hv = og * tanhf(c1);
            union { _Float16 h; unsigned short s; } cv; cv.h = (_Float16)hv;
            __hip_atomic_store(
                (unsigned short*)(h1ring + (size_t)((it + 1) & 1) * RINGE + eidx),
                cv.s, __ATOMIC_RELAXED, __HIP_MEMORY_SCOPE_AGENT);
            if (it == T_STEPS) {
                union { float f; unsigned u; } cf; cf.f = hv;
                __hip_atomic_store((unsigned*)(h1fin + gb * H_SZ + hbase + gu),
                                   cf.u, __ATOMIC_RELAXED, __HIP_MEMORY_SCOPE_AGENT);
            }
        }
        // drain all stores to the coherence point, then arrive on own line
        asm volatile("s_waitcnt vmcnt(0)" ::: "memory");
        __syncthreads();
        if (tid == 0)
            __hip_atomic_store(&flags[(size_t)jb * FLAG_STRIDE], (unsigned)(it + 1),
                               __ATOMIC_RELAXED, __HIP_MEMORY_SCOPE_AGENT);

        // tail: prefetch + convert x[it+1] during barrier slack
        PREFETCH_X(it + 1);
    }

    // final barrier: all h1fin stores visible
    if (tid < 64) {
        while (__hip_atomic_load(&flags[(size_t)lane * FLAG_STRIDE],
                                 __ATOMIC_RELAXED, __HIP_MEMORY_SCOPE_AGENT)
               < (unsigned)(T_STEPS + 1)) { }
    }
    __syncthreads();

    // shut the heaters down, then compute the head
    if (tid == 0)
        __hip_atomic_store(done, 1u, __ATOMIC_RELAXED, __HIP_MEMORY_SCOPE_AGENT);

    // ---- output head: block jb -> out[:, jb] ----
    {
        const int b = tid & 31, kc = tid >> 5;
        float part = 0.f;
        for (int k = kc * 64; k < kc * 64 + 64; ++k) {
            union { unsigned u; float f; } cv;
            cv.u = __hip_atomic_load((const unsigned*)(h1fin + b * H_SZ + k),
                                     __ATOMIC_RELAXED, __HIP_MEMORY_SCOPE_AGENT);
            part += cv.f * Wout[(size_t)k * NC_SZ + jb];
        }
        ps[kc * 32 + b] = part;
        __syncthreads();
        if (tid < 32) {
            float acc = bout[jb];
            #pragma unroll
            for (int c = 0; c < 8; ++c) acc += ps[c * 32 + tid];
            out[tid * NC_SZ + jb] = acc;
        }
    }
#undef PREFETCH_X
}

extern "C" void kernel_launch(void* const* d_in, const int* in_sizes, int n_in,
                              void* d_out, int out_size, void* d_ws, size_t ws_size,
                              hipStream_t stream) {
    const float* feats = (const float*)d_in[0];
    const float* Wi0   = (const float*)d_in[1];
    const float* Wh0   = (const float*)d_in[2];
    const float* bh0   = (const float*)d_in[3];
    const float* Wi1   = (const float*)d_in[4];
    const float* Wh1   = (const float*)d_in[5];
    const float* bh1   = (const float*)d_in[6];
    const float* Wout  = (const float*)d_in[7];
    const float* bout  = (const float*)d_in[8];

    char* ws = (char*)d_ws;
    _Float16* h0ring = (_Float16*)(ws);           // 2 slots * 32 KB
    _Float16* h1ring = (_Float16*)(ws + 131072);  // 2 slots * 32 KB
    float*    h1fin  = (float*)(ws + 262144);     // 64 KB
    unsigned* flags  = (unsigned*)(ws + 327680);  // 64 * 128 B = 8 KB
    unsigned* done   = (unsigned*)(ws + 335872);  // heater shutdown flag

    // zero rings (h[-1]=h[-2]=0), final buf, flags, done — every call
    // (graph replays reuse ws; stale flags/done MUST be cleared each call)
    hipMemsetAsync(d_ws, 0, 339968, stream);

    lstm_persistent<<<dim3(NGRID), dim3(256), 0, stream>>>(
        feats, Wi0, Wh0, bh0, Wi1, Wh1, bh1, Wout, bout,
        (float*)d_out, h0ring, h1ring, h1fin, flags, done);
}

// Round 14
// 18469.789 us; speedup vs baseline: 2.6175x; 2.6175x over previous
//
#include <hip/hip_runtime.h>
#include <math.h>

#define T_STEPS 2048
#define B_SZ 32
#define F_SZ 512
#define H_SZ 512
#define H4_SZ 2048
#define NC_SZ 64
#define NBLK 64
#define RINGE 16384          // fp16 elems per ring slot (32 KB), fragment-ordered
#define FLAG_STRIDE 32       // u32s -> 128 B line per flag
#define REG_SZ 139264        // per-XCD region: h0 64KB | h1 64KB | flags 8KB
#define XCD_AREA (4096 + 8 * REG_SZ)          // 1,118,208
#define R8_AREA 335872
#define COMBO_WS_NEED (XCD_AREA + R8_AREA)    // 1,454,080
#define POLL_CAP (1 << 14)   // fast-fail: broken replica bails in ~ms

typedef _Float16 f16x8 __attribute__((ext_vector_type(8)));
typedef float f32x4 __attribute__((ext_vector_type(4)));

#define TIDX(l, w, rt, ct) (((((l)*4 + (w))*2 + (rt))*2 + (ct)))

// r13/r5 postmortem: BOTH XCD-replica attempts used PLAIN stores for h/flags
// and both died with every replica spinning to bail. Every round that worked
// (r2-r12) stored with sc0sc1 or atomics. Conclusion under test: gfx950 L1 is
// NOT write-through for plain stores -> producer data never reached the XCD
// L2 that sc0 polls read. Fix: ALL cross-block stores are explicit sc0
// (write-through/L1-bypass, still XCD-local - no sc1, no LLC involvement).
#define ST16_SC0(p_, v_)                                                        \
    asm volatile("global_store_short %0, %1, off sc0"                           \
                 :: "v"(p_), "v"((unsigned)(v_)) : "memory")
#define ST32_SC0(p_, v_)                                                        \
    asm volatile("global_store_dword %0, %1, off sc0"                           \
                 :: "v"(p_), "v"((unsigned)(v_)) : "memory")

// Fragment-ordered ring (r8, proven): slot = [kql(2)][ks(8)][rt(2)][lane(64)][i(8)]
// fp16; consumer wave loads CONTIGUOUS 1KB per dwordx4, one vmcnt for all 16.
#define LDFRAG16_BODY(SC)                                                       \
    "global_load_dwordx4 %0, %16, off " SC "\n\t"                               \
    "global_load_dwordx4 %1, %16, off offset:1024 " SC "\n\t"                   \
    "global_load_dwordx4 %2, %16, off offset:2048 " SC "\n\t"                   \
    "global_load_dwordx4 %3, %16, off offset:3072 " SC "\n\t"                   \
    "global_load_dwordx4 %4, %17, off " SC "\n\t"                               \
    "global_load_dwordx4 %5, %17, off offset:1024 " SC "\n\t"                   \
    "global_load_dwordx4 %6, %17, off offset:2048 " SC "\n\t"                   \
    "global_load_dwordx4 %7, %17, off offset:3072 " SC "\n\t"                   \
    "global_load_dwordx4 %8, %18, off " SC "\n\t"                               \
    "global_load_dwordx4 %9, %18, off offset:1024 " SC "\n\t"                   \
    "global_load_dwordx4 %10, %18, off offset:2048 " SC "\n\t"                  \
    "global_load_dwordx4 %11, %18, off offset:3072 " SC "\n\t"                  \
    "global_load_dwordx4 %12, %19, off " SC "\n\t"                              \
    "global_load_dwordx4 %13, %19, off offset:1024 " SC "\n\t"                  \
    "global_load_dwordx4 %14, %19, off offset:2048 " SC "\n\t"                  \
    "global_load_dwordx4 %15, %19, off offset:3072 " SC "\n\t"                  \
    "s_waitcnt vmcnt(0)"

#define LDFRAG16_OUTS(d)                                                        \
    : "=&v"(d[0][0]), "=&v"(d[1][0]), "=&v"(d[0][1]), "=&v"(d[1][1]),           \
      "=&v"(d[0][2]), "=&v"(d[1][2]), "=&v"(d[0][3]), "=&v"(d[1][3]),           \
      "=&v"(d[0][4]), "=&v"(d[1][4]), "=&v"(d[0][5]), "=&v"(d[1][5]),           \
      "=&v"(d[0][6]), "=&v"(d[1][6]), "=&v"(d[0][7]), "=&v"(d[1][7])

#define LDFRAG16_CP(d, a0, a1, a2, a3)                                          \
  asm volatile(LDFRAG16_BODY("sc0 sc1") LDFRAG16_OUTS(d)                        \
    : "v"(a0), "v"(a1), "v"(a2), "v"(a3) : "memory")

#define LDFRAG16_L2(d, a0, a1, a2, a3)                                          \
  asm volatile(LDFRAG16_BODY("sc0") LDFRAG16_OUTS(d)                            \
    : "v"(a0), "v"(a1), "v"(a2), "v"(a3) : "memory")

#define PREFETCH_X(tt_) do {                                                         \
    if (wv < 2 && (tt_) < T_STEPS) {                                                 \
        _Pragma("unroll")                                                            \
        for (int rt = 0; rt < 2; ++rt) {                                             \
            const float* xr = feats                                                  \
                + ((size_t)(rt * 16 + rlane) * T_STEPS + (size_t)(tt_)) * F_SZ       \
                + 256 * wv + klo;                                                    \
            _Pragma("unroll")                                                        \
            for (int ks = 0; ks < 8; ++ks) {                                         \
                const float4 p0 = *(const float4*)(xr + 32 * ks);                    \
                const float4 p1 = *(const float4*)(xr + 32 * ks + 4);                \
                f16x8 t;                                                             \
                t[0] = (_Float16)p0.x; t[1] = (_Float16)p0.y;                        \
                t[2] = (_Float16)p0.z; t[3] = (_Float16)p0.w;                        \
                t[4] = (_Float16)p1.x; t[5] = (_Float16)p1.y;                        \
                t[6] = (_Float16)p1.z; t[7] = (_Float16)p1.w;                        \
                xf[rt][ks] = t;                                                      \
            }                                                                        \
        }                                                                            \
    }                                                                                \
} while (0)

#define LOAD_WEIGHTS()                                                               \
    _Pragma("unroll")                                                                \
    for (int ct = 0; ct < 2; ++ct) {                                                 \
        const int cc   = ct * 16 + rlane;                                            \
        const int jcol = (cc >> 3) * H_SZ + hbase + (cc & 7);                        \
        _Pragma("unroll")                                                            \
        for (int ks = 0; ks < 8; ++ks) {                                             \
            const int k0 = 256 * wv + 32 * ks + klo;                                 \
            f16x8 f0, f1;                                                            \
            _Pragma("unroll")                                                        \
            for (int i = 0; i < 8; ++i) {                                            \
                const int k = k0 + i;                                                \
                const float v0 = (k < H_SZ) ? Wi0[(size_t)k * H4_SZ + jcol]          \
                                : Wh0[(size_t)(k - H_SZ) * H4_SZ + jcol];            \
                const float v1 = (k < H_SZ) ? Wh1[(size_t)k * H4_SZ + jcol]          \
                                : Wi1[(size_t)(k - H_SZ) * H4_SZ + jcol];            \
                f0[i] = (_Float16)v0;                                                \
                f1[i] = (_Float16)v1;                                                \
            }                                                                        \
            wf0[ct][ks] = f0;                                                        \
            wf1[ct][ks] = f1;                                                        \
        }                                                                            \
    }

#define GATES(L, bias, creg, outstmt) do {                                           \
    float z[4];                                                                      \
    _Pragma("unroll")                                                                \
    for (int g = 0; g < 4; ++g) {                                                    \
        const int cc = g * 8 + gu, ct = cc >> 4, col = cc & 15;                      \
        float v = bias[g];                                                           \
        _Pragma("unroll")                                                            \
        for (int w = 0; w < 4; ++w)                                                  \
            v += zs[TIDX(L, w, grt, ct) * 272 + grow * 17 + col];                    \
        z[g] = v;                                                                    \
    }                                                                                \
    const float ig = 1.f / (1.f + expf(-z[0]));                                      \
    const float fg = 1.f / (1.f + expf(-z[1]));                                      \
    const float gg = tanhf(z[2]);                                                    \
    const float og = 1.f / (1.f + expf(-z[3]));                                      \
    creg = fg * creg + ig * gg;                                                      \
    const float hv = og * tanhf(creg);                                               \
    outstmt;                                                                         \
} while (0)

#define MFMA_QUAD(arr0, arr1, wf)                                                    \
    f32x4 a00 = {0,0,0,0}, a01 = {0,0,0,0}, a10 = {0,0,0,0}, a11 = {0,0,0,0};        \
    _Pragma("unroll")                                                                \
    for (int ks = 0; ks < 8; ++ks) {                                                 \
        a00 = __builtin_amdgcn_mfma_f32_16x16x32_f16(arr0, wf[0][ks], a00, 0, 0, 0); \
        a01 = __builtin_amdgcn_mfma_f32_16x16x32_f16(arr0, wf[1][ks], a01, 0, 0, 0); \
        a10 = __builtin_amdgcn_mfma_f32_16x16x32_f16(arr1, wf[0][ks], a10, 0, 0, 0); \
        a11 = __builtin_amdgcn_mfma_f32_16x16x32_f16(arr1, wf[1][ks], a11, 0, 0, 0); \
    }

#define ZS_STORE(L)                                                                  \
    _Pragma("unroll")                                                                \
    for (int q = 0; q < 4; ++q) {                                                    \
        zs[TIDX(L, wv, 0, 0) * 272 + (r0 + q) * 17 + ccl] = a00[q];                  \
        zs[TIDX(L, wv, 0, 1) * 272 + (r0 + q) * 17 + ccl] = a01[q];                  \
        zs[TIDX(L, wv, 1, 0) * 272 + (r0 + q) * 17 + ccl] = a10[q];                  \
        zs[TIDX(L, wv, 1, 1) * 272 + (r0 + q) * 17 + ccl] = a11[q];                  \
    }

// ============ Kernel A: XCD replicas (sc0 write-through stores) ============
// 512 blocks x 256 thr (2/CU). Blocks self-group by XCC_ID into 8 replicas;
// each replica with 64 members runs the full recurrence XCD-locally.
// A completed replica writes out + sets success (+alldone to free others).
// Any stall bails in ~POLL_CAP polls -> kernel B (r8) takes over.
__global__ __launch_bounds__(256, 2) void lstm_xcd(
    const float* __restrict__ feats,
    const float* __restrict__ Wi0, const float* __restrict__ Wh0,
    const float* __restrict__ bh0,
    const float* __restrict__ Wi1, const float* __restrict__ Wh1,
    const float* __restrict__ bh1,
    const float* __restrict__ Wout, const float* __restrict__ bout,
    float* __restrict__ out,
    char* __restrict__ wsbase)
{
    const int tid   = threadIdx.x;
    const int lane  = tid & 63;
    const int wv    = tid >> 6;
    const int rlane = lane & 15;
    const int klo   = (lane >> 4) * 8;

    __shared__ float zs[32 * 272];
    __shared__ float ps[256];
    __shared__ unsigned role_s;
    __shared__ int dead_s;

    unsigned xcc;
    asm volatile("s_getreg_b32 %0, hwreg(HW_REG_XCC_ID)" : "=s"(xcc));
    xcc &= 7;
    unsigned* ctr     = (unsigned*)(wsbase + (size_t)xcc * 128);
    unsigned* alldone = (unsigned*)(wsbase + 1024);
    unsigned* success = (unsigned*)(wsbase + 1152);
    if (tid == 0) {
        role_s = __hip_atomic_fetch_add(ctr, 1u, __ATOMIC_RELAXED,
                                        __HIP_MEMORY_SCOPE_AGENT);
        dead_s = 0;
    }
    __syncthreads();
    const unsigned role = role_s;
    if (role >= 64) return;
    const int jb    = (int)role;
    const int hbase = jb * 8;

    char* regn = wsbase + 4096 + (size_t)xcc * REG_SZ;
    _Float16* h0ring = (_Float16*)regn;               // 2 x 32KB, frag-ordered
    _Float16* h1ring = (_Float16*)(regn + 65536);     // 2 x 32KB
    unsigned* flags  = (unsigned*)(regn + 131072);    // 64 x 128B

    f16x8 wf0[2][8], wf1[2][8];
    LOAD_WEIGHTS();

    const int gb = tid >> 3, gu = tid & 7;
    const int grow = gb & 15, grt = gb >> 4;
    float c0 = 0.f, c1 = 0.f;
    float bias0[4], bias1[4];
    #pragma unroll
    for (int g = 0; g < 4; ++g) {
        bias0[g] = bh0[g * H_SZ + hbase + gu];
        bias1[g] = bh1[g * H_SZ + hbase + gu];
    }
    const int eidx = (jb >> 5) * 8192
                   + ((((jb >> 2) & 7) * 2) + (gb >> 4)) * 512
                   + ((jb & 3) * 16 + (gb & 15)) * 8 + gu;

    f16x8 xf[2][8];
    PREFETCH_X(0);

#define POLL_XCD(val_) do {                                                          \
    if (tid < 64) {                                                                  \
        const unsigned* fp_ = flags + (size_t)lane * FLAG_STRIDE;                    \
        unsigned f_; int spins_ = 0;                                                 \
        for (;;) {                                                                   \
            asm volatile("global_load_dword %0, %1, off sc0\n\t"                     \
                         "s_waitcnt vmcnt(0)"                                        \
                         : "=&v"(f_) : "v"(fp_) : "memory");                         \
            if (f_ >= (unsigned)(val_)) break;                                       \
            if ((++spins_ & 63) == 0) {                                              \
                unsigned ad_;                                                        \
                asm volatile("global_load_dword %0, %1, off sc0 sc1\n\t"             \
                             "s_waitcnt vmcnt(0)"                                    \
                             : "=&v"(ad_) : "v"(alldone) : "memory");                \
                if (ad_ || spins_ > POLL_CAP) { dead_s = 1; break; }                 \
            }                                                                        \
        }                                                                            \
    }                                                                                \
    __syncthreads();                                                                 \
    if (dead_s) return;                                                              \
} while (0)

    for (int it = 0; it <= T_STEPS; ++it) {
        POLL_XCD(it);

        f16x8 hA[2][8];
        if (wv >= 2) {
            const _Float16* b = h0ring + (size_t)((it + 1) & 1) * RINGE
                                + (wv - 2) * 8192 + lane * 8;
            LDFRAG16_L2(hA, b, b + 2048, b + 4096, b + 6144);
        } else if (it > 0) {
            const _Float16* b = h1ring + (size_t)(it & 1) * RINGE
                                + wv * 8192 + lane * 8;
            LDFRAG16_L2(hA, b, b + 2048, b + 4096, b + 6144);
        }

        const int r0 = (lane >> 4) * 4, ccl = lane & 15;

        if (it < T_STEPS) {
            if (wv < 2) { MFMA_QUAD(xf[0][ks], xf[1][ks], wf0); ZS_STORE(0); }
            else        { MFMA_QUAD(hA[0][ks], hA[1][ks], wf0); ZS_STORE(0); }
        }
        if (it > 0) {
            MFMA_QUAD(hA[0][ks], hA[1][ks], wf1); ZS_STORE(1);
        }
        __syncthreads();

        if (it < T_STEPS) {
            GATES(0, bias0, c0, {
                union { _Float16 h; unsigned short s; } cv; cv.h = (_Float16)hv;
                _Float16* p = h0ring + (size_t)(it & 1) * RINGE + eidx;
                ST16_SC0(p, cv.s);
            });
        }
        if (it > 0) {
            GATES(1, bias1, c1, {
                union { _Float16 h; unsigned short s; } cv; cv.h = (_Float16)hv;
                _Float16* p = h1ring + (size_t)((it + 1) & 1) * RINGE + eidx;
                ST16_SC0(p, cv.s);
            });
        }
        asm volatile("s_waitcnt vmcnt(0)" ::: "memory");  // sc0 stores -> L2
        __syncthreads();
        if (tid == 0)
            ST32_SC0(flags + (size_t)jb * FLAG_STRIDE, (unsigned)(it + 1));

        PREFETCH_X(it + 1);
    }

    POLL_XCD(T_STEPS + 1);

    // head: block jb -> out[:, jb]; h1[T-1] lives in slot (T_STEPS+1)&1
    {
        const _Float16* hf = h1ring + (size_t)((T_STEPS + 1) & 1) * RINGE;
        const int b = tid & 31, kc = tid >> 5;
        float part = 0.f;
        #pragma unroll
        for (int o = 0; o < 8; ++o) {
            const int k0 = kc * 64 + o * 8;
            const int idx = (k0 >> 8) * 8192
                          + (((k0 >> 5) & 7) * 2 + (b >> 4)) * 512
                          + (((k0 >> 3) & 3) * 16 + (b & 15)) * 8;
            f16x8 hv8;
            asm volatile("global_load_dwordx4 %0, %1, off sc0\n\t"
                         "s_waitcnt vmcnt(0)"
                         : "=&v"(hv8) : "v"(hf + idx) : "memory");
            #pragma unroll
            for (int j = 0; j < 8; ++j)
                part += (float)hv8[j] * Wout[(size_t)(k0 + j) * NC_SZ + jb];
        }
        ps[kc * 32 + b] = part;
        __syncthreads();
        if (tid < 32) {
            float acc = bout[jb];
            #pragma unroll
            for (int c = 0; c < 8; ++c) acc += ps[c * 32 + tid];
            out[tid * NC_SZ + jb] = acc;
        }
    }
    // out written by this block; mark success + release starved replicas
    asm volatile("s_waitcnt vmcnt(0)" ::: "memory");
    __syncthreads();
    if (tid == 0) {
        __hip_atomic_store(success, 1u, __ATOMIC_RELAXED, __HIP_MEMORY_SCOPE_AGENT);
        __hip_atomic_store(alldone, 1u, __ATOMIC_RELAXED, __HIP_MEMORY_SCOPE_AGENT);
    }
#undef POLL_XCD
}

// ============ Kernel B: r8 fallback (proven 26.3ms); skips if A succeeded ============
__global__ __launch_bounds__(256, 1) void lstm_persistent(
    const float* __restrict__ feats,
    const float* __restrict__ Wi0, const float* __restrict__ Wh0,
    const float* __restrict__ bh0,
    const float* __restrict__ Wi1, const float* __restrict__ Wh1,
    const float* __restrict__ bh1,
    const float* __restrict__ Wout, const float* __restrict__ bout,
    float* __restrict__ out,
    _Float16* __restrict__ h0ring, _Float16* __restrict__ h1ring,
    float* __restrict__ h1fin, unsigned* __restrict__ flags,
    const unsigned* __restrict__ success)
{
    if (__hip_atomic_load(success, __ATOMIC_RELAXED, __HIP_MEMORY_SCOPE_AGENT))
        return;   // kernel A fully wrote out (runs after A completes, same stream)

    const int tid   = threadIdx.x;
    const int lane  = tid & 63;
    const int wv    = tid >> 6;
    const int jb    = blockIdx.x;
    const int hbase = jb * 8;
    const int rlane = lane & 15;
    const int klo   = (lane >> 4) * 8;

    __shared__ float zs[32 * 272];
    __shared__ float ps[256];

    f16x8 wf0[2][8], wf1[2][8];
    LOAD_WEIGHTS();

    const int gb = tid >> 3, gu = tid & 7;
    const int grow = gb & 15, grt = gb >> 4;
    float c0 = 0.f, c1 = 0.f;
    float bias0[4], bias1[4];
    #pragma unroll
    for (int g = 0; g < 4; ++g) {
        bias0[g] = bh0[g * H_SZ + hbase + gu];
        bias1[g] = bh1[g * H_SZ + hbase + gu];
    }
    const int eidx = (jb >> 5) * 8192
                   + ((((jb >> 2) & 7) * 2) + (gb >> 4)) * 512
                   + ((jb & 3) * 16 + (gb & 15)) * 8 + gu;

    f16x8 xf[2][8];
    PREFETCH_X(0);

    for (int it = 0; it <= T_STEPS; ++it) {
        if (tid < 64) {
            while (__hip_atomic_load(&flags[(size_t)lane * FLAG_STRIDE],
                                     __ATOMIC_RELAXED, __HIP_MEMORY_SCOPE_AGENT)
                   < (unsigned)it) { }
        }
        __syncthreads();

        f16x8 hA[2][8];
        if (wv >= 2) {
            const _Float16* b = h0ring + (size_t)((it + 1) & 1) * RINGE
                                + (wv - 2) * 8192 + lane * 8;
            LDFRAG16_CP(hA, b, b + 2048, b + 4096, b + 6144);
        } else if (it > 0) {
            const _Float16* b = h1ring + (size_t)(it & 1) * RINGE
                                + wv * 8192 + lane * 8;
            LDFRAG16_CP(hA, b, b + 2048, b + 4096, b + 6144);
        }

        const int r0 = (lane >> 4) * 4, ccl = lane & 15;

        if (it < T_STEPS) {
            if (wv < 2) { MFMA_QUAD(xf[0][ks], xf[1][ks], wf0); ZS_STORE(0); }
            else        { MFMA_QUAD(hA[0][ks], hA[1][ks], wf0); ZS_STORE(0); }
        }
        if (it > 0) {
            MFMA_QUAD(hA[0][ks], hA[1][ks], wf1); ZS_STORE(1);
        }
        __syncthreads();

        if (it < T_STEPS) {
            GATES(0, bias0, c0, {
                union { _Float16 h; unsigned short s; } cv; cv.h = (_Float16)hv;
                __hip_atomic_store(
                    (unsigned short*)(h0ring + (size_t)(it & 1) * RINGE + eidx),
                    cv.s, __ATOMIC_RELAXED, __HIP_MEMORY_SCOPE_AGENT);
            });
        }
        if (it > 0) {
            GATES(1, bias1, c1, {
                union { _Float16 h; unsigned short s; } cv; cv.h = (_Float16)hv;
                __hip_atomic_store(
                    (unsigned short*)(h1ring + (size_t)((it + 1) & 1) * RINGE + eidx),
                    cv.s, __ATOMIC_RELAXED, __HIP_MEMORY_SCOPE_AGENT);
                if (it == T_STEPS) {
                    union { float f; unsigned u; } cf; cf.f = hv;
                    __hip_atomic_store((unsigned*)(h1fin + gb * H_SZ + hbase + gu),
                                       cf.u, __ATOMIC_RELAXED,
                                       __HIP_MEMORY_SCOPE_AGENT);
                }
            });
        }
        asm volatile("s_waitcnt vmcnt(0)" ::: "memory");
        __syncthreads();
        if (tid == 0)
            __hip_atomic_store(&flags[(size_t)jb * FLAG_STRIDE], (unsigned)(it + 1),
                               __ATOMIC_RELAXED, __HIP_MEMORY_SCOPE_AGENT);

        PREFETCH_X(it + 1);
    }

    if (tid < 64) {
        while (__hip_atomic_load(&flags[(size_t)lane * FLAG_STRIDE],
                                 __ATOMIC_RELAXED, __HIP_MEMORY_SCOPE_AGENT)
               < (unsigned)(T_STEPS + 1)) { }
    }
    __syncthreads();

    {
        const int b = tid & 31, kc = tid >> 5;
        float part = 0.f;
        for (int k = kc * 64; k < kc * 64 + 64; ++k) {
            union { unsigned u; float f; } cv;
            cv.u = __hip_atomic_load((const unsigned*)(h1fin + b * H_SZ + k),
                                     __ATOMIC_RELAXED, __HIP_MEMORY_SCOPE_AGENT);
            part += cv.f * Wout[(size_t)k * NC_SZ + jb];
        }
        ps[kc * 32 + b] = part;
        __syncthreads();
        if (tid < 32) {
            float acc = bout[jb];
            #pragma unroll
            for (int c = 0; c < 8; ++c) acc += ps[c * 32 + tid];
            out[tid * NC_SZ + jb] = acc;
        }
    }
}

extern "C" void kernel_launch(void* const* d_in, const int* in_sizes, int n_in,
                              void* d_out, int out_size, void* d_ws, size_t ws_size,
                              hipStream_t stream) {
    const float* feats = (const float*)d_in[0];
    const float* Wi0   = (const float*)d_in[1];
    const float* Wh0   = (const float*)d_in[2];
    const float* bh0   = (const float*)d_in[3];
    const float* Wi1   = (const float*)d_in[4];
    const float* Wh1   = (const float*)d_in[5];
    const float* bh1   = (const float*)d_in[6];
    const float* Wout  = (const float*)d_in[7];
    const float* bout  = (const float*)d_in[8];

    if (ws_size >= (size_t)COMBO_WS_NEED) {
        // [0, XCD_AREA): counters/alldone/success + 8 per-XCD regions.
        // [XCD_AREA, +R8_AREA): kernel B rings/h1fin/flags.
        // Zero all each call (graph replays reuse ws).
        hipMemsetAsync(d_ws, 0, COMBO_WS_NEED, stream);
        char* ws = (char*)d_ws;
        char* r8 = ws + XCD_AREA;
        lstm_xcd<<<dim3(512), dim3(256), 0, stream>>>(
            feats, Wi0, Wh0, bh0, Wi1, Wh1, bh1, Wout, bout,
            (float*)d_out, ws);
        lstm_persistent<<<dim3(NBLK), dim3(256), 0, stream>>>(
            feats, Wi0, Wh0, bh0, Wi1, Wh1, bh1, Wout, bout,
            (float*)d_out,
            (_Float16*)(r8), (_Float16*)(r8 + 131072),
            (float*)(r8 + 262144), (unsigned*)(r8 + 327680),
            (const unsigned*)(ws + 1152));
    } else {
        // r8-only fallback; success word (zeroed) lives past the r8 area
        char* ws = (char*)d_ws;
        hipMemsetAsync(d_ws, 0, R8_AREA + 128, stream);
        lstm_persistent<<<dim3(NBLK), dim3(256), 0, stream>>>(
            feats, Wi0, Wh0, bh0, Wi1, Wh1, bh1, Wout, bout,
            (float*)d_out,
            (_Float16*)(ws), (_Float16*)(ws + 131072),
            (float*)(ws + 262144), (unsigned*)(ws + 327680),
            (const unsigned*)(ws + R8_AREA));
    }
}